// Round 1
// baseline (402.585 us; speedup 1.0000x reference)
//
#include <hip/hip_runtime.h>
#include <stdint.h>

#define B_ 4
#define H_ 16
#define NQ_ 1024
#define NK_ 1024
#define DM_ 1024
#define DK_ 64

typedef __attribute__((ext_vector_type(8))) short short8;
typedef __attribute__((ext_vector_type(4))) float f32x4;
typedef unsigned short u16;
typedef unsigned int u32;

__device__ __forceinline__ u16 f2bf(float f) {
  u32 u = __builtin_bit_cast(u32, f);
  u32 r = u + 0x7fffu + ((u >> 16) & 1u);
  return (u16)(r >> 16);
}

__device__ __forceinline__ short8 ld_short8(const u16* p) {
  return __builtin_bit_cast(short8, *(const int4*)p);
}

// ---------------------------------------------------------------------------
// Mask storage detector: bool (1 byte/elem) vs int32 (4 bytes/elem).
// If int32 with values 0/1, every byte at offset%4 != 0 is zero.
// ---------------------------------------------------------------------------
__global__ void detect_mask_kernel(const unsigned char* __restrict__ m, int* __restrict__ flag) {
  if (threadIdx.x == 0) {
    int f = 0;
    for (int i = 0; i < 256; ++i)
      if ((i & 3) != 0 && m[i] != 0) f = 1;
    *flag = f;  // 1 => byte mask, 0 => int32 mask
  }
}

// ---------------------------------------------------------------------------
// GEMM: C[m][n] = sum_k A[m][k] * W[n][k] + bias[n]
// modes 0/1/2: A = queries/keys/values (fp32), out -> bf16 q/k natural layout
//              [b,h,t,d]; mode 2 writes V TRANSPOSED [b,h,d,t].
// mode 3: A = obuf (bf16), W = Wo, out -> fp32 d_out (+bias).
// 128x128 tile, BK=32, 4 waves (2x2 of 64x64), 16x16x32 bf16 MFMA.
// ---------------------------------------------------------------------------
__global__ __launch_bounds__(256) void gemm_kernel(
    const float* __restrict__ Aq, const float* __restrict__ Ak, const float* __restrict__ Av,
    const u16* __restrict__ Ao,
    const float* __restrict__ Wq, const float* __restrict__ Wk,
    const float* __restrict__ Wv, const float* __restrict__ Wo,
    const float* __restrict__ bq, const float* __restrict__ bk,
    const float* __restrict__ bv, const float* __restrict__ bo,
    u16* __restrict__ qbuf, u16* __restrict__ kbuf, u16* __restrict__ vTbuf,
    float* __restrict__ outbuf, int mode_base)
{
  const int z = mode_base + (int)blockIdx.z;
  const int n0 = blockIdx.x * 128;
  const int m0 = blockIdx.y * 128;
  const int tid = threadIdx.x;
  const int lane = tid & 63;
  const int wave = tid >> 6;
  const int wm = wave >> 1, wn = wave & 1;

  // padded LDS tiles: stride 40 bf16 = 80 B (16B-aligned rows, conflict-free b128)
  __shared__ u16 Al[128 * 40];
  __shared__ u16 Bl[128 * 40];

  const float* Af = (z == 0) ? Aq : (z == 1 ? Ak : Av);
  const float* W  = (z == 0) ? Wq : (z == 1 ? Wk : (z == 2 ? Wv : Wo));

  f32x4 acc[4][4];
#pragma unroll
  for (int i = 0; i < 4; ++i)
#pragma unroll
    for (int j = 0; j < 4; ++j) acc[i][j] = (f32x4){0.f, 0.f, 0.f, 0.f};

  float4 arf[4];
  int4   arb[2];
  float4 brf[4];

  auto load_tiles = [&](int ks) {
    const int kk0 = ks * 32;
    if (z < 3) {
#pragma unroll
      for (int c = 0; c < 4; ++c) {
        int chunk = c * 256 + tid;
        arf[c] = *(const float4*)(Af + (size_t)(m0 + (chunk >> 3)) * DM_ + kk0 + (chunk & 7) * 4);
      }
    } else {
#pragma unroll
      for (int c = 0; c < 2; ++c) {
        int chunk = c * 256 + tid;
        arb[c] = *(const int4*)(Ao + (size_t)(m0 + (chunk >> 2)) * DM_ + kk0 + (chunk & 3) * 8);
      }
    }
#pragma unroll
    for (int c = 0; c < 4; ++c) {
      int chunk = c * 256 + tid;
      brf[c] = *(const float4*)(W + (size_t)(n0 + (chunk >> 3)) * DM_ + kk0 + (chunk & 7) * 4);
    }
  };

  auto store_lds = [&]() {
    if (z < 3) {
#pragma unroll
      for (int c = 0; c < 4; ++c) {
        int chunk = c * 256 + tid;
        ushort4 p;
        p.x = f2bf(arf[c].x); p.y = f2bf(arf[c].y); p.z = f2bf(arf[c].z); p.w = f2bf(arf[c].w);
        *(ushort4*)(Al + (chunk >> 3) * 40 + (chunk & 7) * 4) = p;
      }
    } else {
#pragma unroll
      for (int c = 0; c < 2; ++c) {
        int chunk = c * 256 + tid;
        *(int4*)(Al + (chunk >> 2) * 40 + (chunk & 3) * 8) = arb[c];
      }
    }
#pragma unroll
    for (int c = 0; c < 4; ++c) {
      int chunk = c * 256 + tid;
      ushort4 p;
      p.x = f2bf(brf[c].x); p.y = f2bf(brf[c].y); p.z = f2bf(brf[c].z); p.w = f2bf(brf[c].w);
      *(ushort4*)(Bl + (chunk >> 3) * 40 + (chunk & 7) * 4) = p;
    }
  };

  load_tiles(0);
  for (int ks = 0; ks < 32; ++ks) {
    __syncthreads();
    store_lds();
    __syncthreads();
    if (ks < 31) load_tiles(ks + 1);
    short8 afr[4], bfr[4];
#pragma unroll
    for (int i = 0; i < 4; ++i) {
      afr[i] = ld_short8(Al + (wm * 64 + i * 16 + (lane & 15)) * 40 + (lane >> 4) * 8);
      bfr[i] = ld_short8(Bl + (wn * 64 + i * 16 + (lane & 15)) * 40 + (lane >> 4) * 8);
    }
#pragma unroll
    for (int i = 0; i < 4; ++i)
#pragma unroll
      for (int j = 0; j < 4; ++j)
        acc[i][j] = __builtin_amdgcn_mfma_f32_16x16x32_bf16(afr[i], bfr[j], acc[i][j], 0, 0, 0);
  }

  // epilogue. D layout: col = lane&15, row = (lane>>4)*4 + r
  const float* bias = (z == 0) ? bq : (z == 1 ? bk : (z == 2 ? bv : bo));
#pragma unroll
  for (int i = 0; i < 4; ++i) {
    const int token0 = m0 + wm * 64 + i * 16 + (lane >> 4) * 4;
#pragma unroll
    for (int j = 0; j < 4; ++j) {
      const int feat = n0 + wn * 64 + j * 16 + (lane & 15);
      const float bvl = bias[feat];
      if (z == 3) {
#pragma unroll
        for (int r = 0; r < 4; ++r)
          outbuf[(size_t)(token0 + r) * DM_ + feat] = acc[i][j][r] + bvl;
      } else if (z == 2) {
        // V transposed: [b,h,d,t]; 4 consecutive tokens -> ushort4
        const int bb = token0 >> 10, t = token0 & 1023;
        const int hh = feat >> 6, d = feat & 63;
        ushort4 p;
        p.x = f2bf(acc[i][j][0] + bvl);
        p.y = f2bf(acc[i][j][1] + bvl);
        p.z = f2bf(acc[i][j][2] + bvl);
        p.w = f2bf(acc[i][j][3] + bvl);
        *(ushort4*)(vTbuf + ((size_t)(bb * H_ + hh) * DK_ + d) * NK_ + t) = p;
      } else {
        u16* dst = (z == 0) ? qbuf : kbuf;
        const int hh = feat >> 6, d = feat & 63;
#pragma unroll
        for (int r = 0; r < 4; ++r) {
          const int token = token0 + r;
          const int bb = token >> 10, t = token & 1023;
          dst[((size_t)(bb * H_ + hh) * NQ_ + t) * DK_ + d] = f2bf(acc[i][j][r] + bvl);
        }
      }
    }
  }
}

// ---------------------------------------------------------------------------
// Attention: per (b,h,32-q-row tile). Full S strip [32][1024] fp32 in LDS
// (XOR-swizzled), softmax in registers, PV via bf16 MFMA from LDS P + vT tile.
// 512 threads = 8 waves (2x4 over q-rows x cols).
// ---------------------------------------------------------------------------
__global__ __launch_bounds__(512) void attn_kernel(
    const u16* __restrict__ qbuf, const u16* __restrict__ kbuf, const u16* __restrict__ vTbuf,
    const float* __restrict__ aw, const void* __restrict__ maskp, const int* __restrict__ flagp,
    float* __restrict__ attout, u16* __restrict__ obuf)
{
  extern __shared__ char smem[];
  float* S = (float*)smem;                    // 32*1024 fp32, col swizzle: c ^ ((row&7)<<2)
  u16* KV = (u16*)(smem + 32 * 1024 * 4);     // [64][72] bf16 staging tile

  const int qt = blockIdx.x, h = blockIdx.y, b = blockIdx.z;
  const int bh = b * H_ + h;
  const int qbase = qt * 32;
  const int tid = threadIdx.x;
  const int lane = tid & 63;
  const int wave = tid >> 6;
  const int wm = wave >> 2, wn = wave & 3;
  const int mflag = *flagp;

  // Q A-fragments (rows wm*16 + lane%16, d split in two 32-chunks)
  short8 qf0, qf1;
  {
    const u16* qp = qbuf + ((size_t)bh * NQ_ + qbase + wm * 16 + (lane & 15)) * DK_ + (lane >> 4) * 8;
    qf0 = ld_short8(qp);
    qf1 = ld_short8(qp + 32);
  }

  const int srow = tid >> 3;          // 0..63
  const int scol = (tid & 7) * 8;     // 0..56
  int4 stg;

  // ---- QK^T: S[q][k] = sum_d q*k ----
  stg = *(const int4*)(kbuf + ((size_t)bh * NK_ + srow) * DK_ + scol);
  for (int t = 0; t < 16; ++t) {
    __syncthreads();
    *(int4*)(KV + srow * 72 + scol) = stg;
    __syncthreads();
    if (t < 15)
      stg = *(const int4*)(kbuf + ((size_t)bh * NK_ + (t + 1) * 64 + srow) * DK_ + scol);
    const int krow = wn * 16 + (lane & 15);
    short8 kf0 = ld_short8(KV + krow * 72 + (lane >> 4) * 8);
    short8 kf1 = ld_short8(KV + krow * 72 + 32 + (lane >> 4) * 8);
    f32x4 sacc = (f32x4){0.f, 0.f, 0.f, 0.f};
    sacc = __builtin_amdgcn_mfma_f32_16x16x32_bf16(qf0, kf0, sacc, 0, 0, 0);
    sacc = __builtin_amdgcn_mfma_f32_16x16x32_bf16(qf1, kf1, sacc, 0, 0, 0);
    const int coln = t * 64 + wn * 16 + (lane & 15);
#pragma unroll
    for (int r = 0; r < 4; ++r) {
      const int row = wm * 16 + (lane >> 4) * 4 + r;
      S[row * 1024 + (coln ^ ((row & 7) << 2))] = sacc[r];
    }
  }
  __syncthreads();

  // ---- softmax (scale, aw, mask, max-sub, exp, normalize) ----
  {
    const int row = tid >> 4;     // 0..31
    const int ls = tid & 15;
    const size_t abase = ((size_t)bh * NQ_ + qbase + row) * (size_t)NK_;
    float* Srow = S + row * 1024;
    const int swz = (row & 7) << 2;
    const float scale = 0.125f;
    const float NEGINF = -__builtin_inff();
    f32x4 v[16];
    float mx = NEGINF;
#pragma unroll
    for (int i = 0; i < 16; ++i) {
      const int c = ls * 4 + i * 64;
      f32x4 sv = *(const f32x4*)(Srow + (c ^ swz));
      f32x4 a4 = *(const f32x4*)(aw + abase + c);
      int k0, k1, k2, k3;
      if (mflag) {
        uchar4 u = *(const uchar4*)((const unsigned char*)maskp + abase + c);
        k0 = u.x; k1 = u.y; k2 = u.z; k3 = u.w;
      } else {
        int4 u = *(const int4*)((const int*)maskp + abase + c);
        k0 = u.x; k1 = u.y; k2 = u.z; k3 = u.w;
      }
      f32x4 tv;
      tv[0] = k0 ? NEGINF : sv[0] * scale * a4[0];
      tv[1] = k1 ? NEGINF : sv[1] * scale * a4[1];
      tv[2] = k2 ? NEGINF : sv[2] * scale * a4[2];
      tv[3] = k3 ? NEGINF : sv[3] * scale * a4[3];
      v[i] = tv;
      mx = fmaxf(mx, fmaxf(fmaxf(tv[0], tv[1]), fmaxf(tv[2], tv[3])));
    }
#pragma unroll
    for (int o = 8; o >= 1; o >>= 1) mx = fmaxf(mx, __shfl_xor(mx, o, 16));
    float sum = 0.f;
#pragma unroll
    for (int i = 0; i < 16; ++i) {
      f32x4 tv = v[i];
      tv[0] = __expf(tv[0] - mx); tv[1] = __expf(tv[1] - mx);
      tv[2] = __expf(tv[2] - mx); tv[3] = __expf(tv[3] - mx);
      v[i] = tv;
      sum += (tv[0] + tv[1]) + (tv[2] + tv[3]);
    }
#pragma unroll
    for (int o = 8; o >= 1; o >>= 1) sum += __shfl_xor(sum, o, 16);
    const float inv = 1.0f / sum;
#pragma unroll
    for (int i = 0; i < 16; ++i) {
      const int c = ls * 4 + i * 64;
      f32x4 tv = v[i];
      tv[0] *= inv; tv[1] *= inv; tv[2] *= inv; tv[3] *= inv;
      *(f32x4*)(Srow + (c ^ swz)) = tv;
      *(f32x4*)(attout + abase + c) = tv;
    }
  }
  __syncthreads();

  // ---- PV: O[q][d] = sum_t P[q][t] * v[t][d] ----
  f32x4 oacc = (f32x4){0.f, 0.f, 0.f, 0.f};
  stg = *(const int4*)(vTbuf + ((size_t)bh * DK_ + srow) * NK_ + scol);
  const int arow = wm * 16 + (lane & 15);
  const float* Sr = S + arow * 1024;
  const int asw = (arow & 7) << 2;
  const int vrow = wn * 16 + (lane & 15);
  for (int t = 0; t < 16; ++t) {
    __syncthreads();
    *(int4*)(KV + srow * 72 + scol) = stg;
    __syncthreads();
    if (t < 15)
      stg = *(const int4*)(vTbuf + ((size_t)bh * DK_ + srow) * NK_ + (t + 1) * 64 + scol);
#pragma unroll
    for (int kk = 0; kk < 2; ++kk) {
      const int cb = t * 64 + kk * 32 + (lane >> 4) * 8;
      f32x4 p0 = *(const f32x4*)(Sr + (cb ^ asw));
      f32x4 p1 = *(const f32x4*)(Sr + ((cb + 4) ^ asw));
      short8 pa;
      pa[0] = (short)f2bf(p0[0]); pa[1] = (short)f2bf(p0[1]);
      pa[2] = (short)f2bf(p0[2]); pa[3] = (short)f2bf(p0[3]);
      pa[4] = (short)f2bf(p1[0]); pa[5] = (short)f2bf(p1[1]);
      pa[6] = (short)f2bf(p1[2]); pa[7] = (short)f2bf(p1[3]);
      short8 vf = ld_short8(KV + vrow * 72 + kk * 32 + (lane >> 4) * 8);
      oacc = __builtin_amdgcn_mfma_f32_16x16x32_bf16(pa, vf, oacc, 0, 0, 0);
    }
  }
  // write O to obuf [token][h*64+d] bf16
  const int d = wn * 16 + (lane & 15);
  const int feat = h * DK_ + d;
#pragma unroll
  for (int r = 0; r < 4; ++r) {
    const int q = qbase + wm * 16 + (lane >> 4) * 4 + r;
    obuf[((size_t)b * NQ_ + q) * DM_ + feat] = f2bf(oacc[r]);
  }
}

// ---------------------------------------------------------------------------
extern "C" void kernel_launch(void* const* d_in, const int* in_sizes, int n_in,
                              void* d_out, int out_size, void* d_ws, size_t ws_size,
                              hipStream_t stream)
{
  const float* queries = (const float*)d_in[0];
  const float* keys    = (const float*)d_in[1];
  const float* values  = (const float*)d_in[2];
  const float* aw      = (const float*)d_in[3];
  const void*  maskp   = d_in[4];
  const float* Wq = (const float*)d_in[5];
  const float* bq = (const float*)d_in[6];
  const float* Wk = (const float*)d_in[7];
  const float* bk = (const float*)d_in[8];
  const float* Wv = (const float*)d_in[9];
  const float* bv = (const float*)d_in[10];
  const float* Wo = (const float*)d_in[11];
  const float* bo = (const float*)d_in[12];

  char* ws = (char*)d_ws;
  const size_t NE = (size_t)B_ * H_ * NQ_ * DK_;  // 4,194,304 elems per buffer
  int* flag  = (int*)ws;
  u16* qbuf  = (u16*)(ws + 256);
  u16* kbuf  = qbuf + NE;
  u16* vTbuf = kbuf + NE;
  u16* obuf  = vTbuf + NE;
  if (ws_size < 256 + 8 * NE) return;  // ~33.6 MB needed

  float* outp = (float*)d_out;
  float* attp = outp + (size_t)B_ * NQ_ * DM_;

  detect_mask_kernel<<<1, 64, 0, stream>>>((const unsigned char*)maskp, flag);

  // Q,K,V projections (one launch, z selects input/weight/epilogue)
  gemm_kernel<<<dim3(8, 32, 3), 256, 0, stream>>>(queries, keys, values, obuf,
      Wq, Wk, Wv, Wo, bq, bk, bv, bo, qbuf, kbuf, vTbuf, outp, 0);

  const int SMEM = 32 * 1024 * 4 + 64 * 72 * 2;  // 140,288 B
  hipFuncSetAttribute(reinterpret_cast<const void*>(attn_kernel),
                      hipFuncAttributeMaxDynamicSharedMemorySize, SMEM);
  attn_kernel<<<dim3(32, 16, 4), 512, SMEM, stream>>>(qbuf, kbuf, vTbuf, aw, maskp, flag,
                                                      attp, obuf);

  // output projection
  gemm_kernel<<<dim3(8, 32, 1), 256, 0, stream>>>(queries, keys, values, obuf,
      Wq, Wk, Wv, Wo, bq, bk, bv, bo, qbuf, kbuf, vTbuf, outp, 3);
}